// Round 10
// baseline (117.320 us; speedup 1.0000x reference)
//
#include <hip/hip_runtime.h>

#define KK 256
#define NCLS 18
#define NTHREADS 320      // 5 waves: wave 0 = scan, waves 1-4 = producers
#define SCAN_W 64

typedef unsigned long long ull;

// ---------------------------------------------------------------------------
// Fused kernel v2: one block per batch.
//   Wave 0  : serial suppression scan (r7-verified affine row body).
//   Waves1-4: per-pair affine transition planes (r7-verified float exprs),
//             ONE WAVE PER ROW: lane l computes j = l + 64t (conflict-free
//             LDS reads), words assembled via 2x shfl_xor OR in lane-quads.
//             Chunk-pipelined 2 ahead of the scan.
// Plane word per (row i, word l): bit (4*p + q) for pair j = 4l+q:
//   p0=A0 p1=A1 p2=B0 p3=B1 p4=isC p5=M0 p6=M1   (t(x) = a·x ⊕ β per b_j)
// ---------------------------------------------------------------------------
__global__ __launch_bounds__(NTHREADS)
void fused2_suppress_kernel(const float* __restrict__ pc, const float* __restrict__ ps,
                            const float* __restrict__ ph, const float* __restrict__ sem,
                            const float* __restrict__ av, float* __restrict__ out)
{
#pragma clang fp contract(off)
    const int b   = blockIdx.x;
    const int tid = threadIdx.x;
    const int lane = tid & 63;

    __shared__ float sd0[KK], sd1[KK], sd2[KK], sd3[KK], sd4[KK], sd5[KK];
    __shared__ float sp[KK], sn[KK], sc0[KK], sc1[KK], sc2[KK];
    __shared__ unsigned s_mask[KK * 64];   // 64 KB plane words

    const float* pcb  = pc  + (size_t)b * 3 * KK;
    const float* psb  = ps  + (size_t)b * 3 * KK;
    const float* phb  = ph  + (size_t)b * 2 * KK;
    const float* semb = sem + (size_t)b * (2 + NCLS) * KK;
    const float* avb  = av  + (size_t)b * KK * 3;
    float* outb       = out + (size_t)b * KK * 28;

    // ---- stage derived per-proposal data (identical float exprs to ref) ----
    if (tid < KK) {
        const int k = tid;
        const float c0 = avb[k*3+0] + pcb[0*KK + k];
        const float c1 = avb[k*3+1] + pcb[1*KK + k];
        const float c2 = avb[k*3+2] + pcb[2*KK + k];
        const float s0 = psb[0*KK + k], s1 = psb[1*KK + k], s2 = psb[2*KK + k];
        const float h1 = phb[1*KK + k];
        const float v0 = s0 * h1, v1 = s1, v2 = s2 * h1;
        sd0[k] = (v0 + c0) - fabsf(s0);
        sd1[k] = (v0 + c0);
        sd2[k] = (v1 + c1) - fabsf(s1);
        sd3[k] = (v1 + c1);
        sd4[k] = (v2 + c2) - fabsf(s2);
        sd5[k] = (v2 + c2);
        sp[k]  = semb[0*KK + k];
        sn[k]  = semb[1*KK + k];
        sc0[k] = c0; sc1[k] = c1; sc2[k] = c2;
    }
    __syncthreads();   // staging visible

    // ---- pass-through outputs (all threads) ----
    for (int s = tid; s < KK * 28; s += NTHREADS) {
        const int kk = s / 28;
        const int c  = s % 28;
        if (c == 8 || c == 9) continue;      // scores written at the end
        float val;
        if (c < 3)       val = (c == 0) ? sc0[kk] : ((c == 1) ? sc1[kk] : sc2[kk]);
        else if (c < 6)  val = psb[(c - 3) * KK + kk];
        else if (c < 8)  val = phb[(c - 6) * KK + kk];
        else             val = semb[(c - 8) * KK + kk];
        outb[(size_t)kk * 28 + c] = val;
    }

    // ---- producer: one 16-row chunk; wave wid handles rows wid*4 + r ----
    const int wid = (tid >> 6) - 1;   // 0..3 for producer waves
    auto produce = [&](int cc) {
#pragma unroll
        for (int r = 0; r < 4; ++r) {
            const int i = cc * 16 + wid * 4 + r;
            const float piv = sp[i], niv = sn[i];
            const float di0 = sd0[i], di1 = sd1[i], di2 = sd2[i];
            const float di3 = sd3[i], di4 = sd4[i], di5 = sd5[i];
            const float ci0 = sc0[i], ci1 = sc1[i], ci2 = sc2[i];
#pragma unroll
            for (int t = 0; t < 4; ++t) {
                const int j = lane + 64 * t;
                unsigned a0 = 1u, a1 = 1u, b0 = 0u, b1 = 0u, isC = 0u, mm0 = 0u, mm1 = 1u;
                if (j > i) {
                    const float dx = ci0 - sc0[j];
                    const float dy = ci1 - sc1[j];
                    const float dz = ci2 - sc2[j];
                    const float dist2 = dx*dx + dy*dy + dz*dz;
                    if (dist2 < 9.0f) {
                        const float e0 = sd0[j], e1 = sd1[j], e2 = sd2[j];
                        const float e3 = sd3[j], e4 = sd4[j], e5 = sd5[j];
                        const bool case0 = (e0 < di0) & (e1 > di1) & (e2 < di2)
                                         & (e3 > di3) & (e4 < di4) & (e5 > di5);
                        const bool case1 = (e0 > di0) & (e1 < di1) & (e2 > di2)
                                         & (e3 < di3) & (e4 > di4) & (e5 < di5);
                        if (case0) {
                            const unsigned tA0 = (piv < niv) ? 1u : 0u;
                            const unsigned tA1 = (niv < piv) ? 0u : 1u;
                            a0 = a1 = tA0 ^ tA1;
                            b0 = b1 = tA0;
                        } else if (case1) {
                            const float pjv = sp[j], njv = sn[j];
                            mm0 = (pjv < njv) ? 1u : 0u;
                            mm1 = (njv < pjv) ? 0u : 1u;
                        } else {
                            const bool ovx = ((e1 > di0) & (e1 < di1)) | ((di1 > e0) & (di1 < e1));
                            const bool ovy = ((e3 > di2) & (e3 < di3)) | ((di3 > e2) & (di3 < e3));
                            const bool ovz = ((e5 > di4) & (e5 < di5)) | ((di5 > e4) & (di5 < e5));
                            if (ovx & ovy & ovz) {
                                const float pjv = sp[j], njv = sn[j];
                                const unsigned c00 = (niv < njv) ? 1u : 0u;
                                const unsigned c10 = (piv < njv) ? 1u : 0u;
                                const unsigned c01 = (niv < pjv) ? 1u : 0u;
                                const unsigned c11 = (piv < pjv) ? 1u : 0u;
                                isC = 1u;
                                a0 = 1u ^ c00 ^ c10;  b0 = c00;
                                a1 = 1u ^ c01 ^ c11;  b1 = c01;
                            }
                        }
                    }
                }
                const unsigned s = a0 | (a1 << 4) | (b0 << 8) | (b1 << 12)
                                 | (isC << 16) | (mm0 << 20) | (mm1 << 24);
                unsigned x = s << (lane & 3);
                x |= (unsigned)__shfl_xor((int)x, 1, 64);
                x |= (unsigned)__shfl_xor((int)x, 2, 64);
                if ((lane & 3) == 0)
                    s_mask[i * 64 + (lane >> 2) + 16 * t] = x;
            }
        }
    };

    // prologue: chunks 0 and 1
    if (tid >= SCAN_W) { produce(0); produce(1); }

    unsigned bmask = 0;
    const ull belowR = __builtin_bitreverse64((1ull << lane) - 1ull);
    __syncthreads();   // chunks 0,1 ready

    unsigned mcur = (tid < SCAN_W) ? s_mask[lane] : 0u;   // row 0

#define ROWBODY(i_) { \
        const unsigned m = mcur; \
        const int slot = (i_) & 3, owner = (i_) >> 2; \
        const ull bsb = __ballot(((bmask >> slot) & 1u) != 0u); \
        const unsigned b_start = (unsigned)((bsb >> owner) & 1ull); \
        const unsigned A0n = m & 0xFu,         A1n = (m >> 4) & 0xFu; \
        const unsigned B0n = (m >> 8) & 0xFu,  B1n = (m >> 12) & 0xFu; \
        const unsigned isCn = (m >> 16) & 0xFu; \
        const unsigned M0n = (m >> 20) & 0xFu, M1n = (m >> 24) & 0xFu; \
        const unsigned bm = bmask; \
        const unsigned AV  = (A1n & bm) | (A0n & ~bm); \
        const unsigned BV  = (B1n & bm) | (B0n & ~bm); \
        const unsigned bmB = (M1n & bm) | (M0n & ~bm); \
        const unsigned F0s = isCn & ~BV; \
        const unsigned F1s = isCn & (AV ^ BV); \
        const unsigned As = AV << 1; \
        const unsigned Bs = BV << 1; \
        const unsigned B2 = Bs ^ (As & (Bs << 1)); \
        const unsigned A2 = As & (As << 1); \
        const unsigned av0 = B2 ^ (A2 & (B2 << 2)); \
        const unsigned y  = As | 1u; \
        const unsigned z1 = y & ((y << 1) | 1u); \
        const unsigned pa = z1 & ((z1 << 2) | 3u); \
        const unsigned FS  = (AV & av0) ^ BV; \
        const unsigned aTv = pa & AV; \
        const ull b0m = __ballot((FS & 8u) != 0u); \
        const ull b1m = __ballot(((FS ^ aTv) & 8u) != 0u); \
        const ull nm  = b0m & ~b1m; \
        const ull cm  = ~(b0m ^ b1m); \
        const ull cmr = __builtin_bitreverse64(cm); \
        const ull nmr = __builtin_bitreverse64(nm); \
        const ull Wr  = __builtin_bitreverse64(b0m); \
        const ull cbr = cmr & belowR; \
        const ull lb  = cbr & (0ull - cbr); \
        const unsigned vK = ((Wr & lb) != 0ull) ? 1u : 0u; \
        const ull betw = belowR & (lb - 1ull); \
        const unsigned par = (unsigned)__builtin_popcountll(nmr & betw) & 1u; \
        const unsigned excl = ((cbr != 0ull) ? vK : b_start) ^ par; \
        const ull lbA = cmr & (0ull - cmr); \
        const unsigned vKA = ((Wr & lbA) != 0ull) ? 1u : 0u; \
        const unsigned parA = (unsigned)__builtin_popcountll(nmr & (lbA - 1ull)) & 1u; \
        const unsigned bfin = ((cmr != 0ull) ? vKA : b_start) ^ parA; \
        const unsigned Emask = (0u - excl) & 0xFu; \
        const unsigned sv = av0 ^ (pa & Emask); \
        const unsigned flips = (F1s & sv) | (F0s & ~sv); \
        unsigned nbm = bmB ^ flips; \
        const unsigned fixed = (nbm & ~(1u << slot)) | (bfin << slot); \
        bmask = (tid == owner) ? fixed : nbm; }

    for (int cc = 0; cc < 16; ++cc) {
        if (tid >= SCAN_W) {
            if (cc + 2 < 16) produce(cc + 2);
        } else {
            // scan chunk cc; prefetch reaches first row of chunk cc+1 (ready)
#pragma unroll
            for (int r = 0; r < 16; ++r) {
                const int i_ = cc * 16 + r;
                if (i_ == 255) break;
                const unsigned mnext = s_mask[(i_ + 1) * 64 + lane];
                ROWBODY(i_)
                mcur = mnext;
            }
        }
        __syncthreads();
    }
#undef ROWBODY

    // ---- final: suppressed scores ----
    if (tid < SCAN_W) {
#pragma unroll
        for (int q = 0; q < 4; ++q) {
            const int k = lane * 4 + q;
            const unsigned bq = (bmask >> q) & 1u;
            const float p = sp[k], n = sn[k];
            outb[k*28 + 8] = bq ? n : p;
            outb[k*28 + 9] = bq ? p : n;
        }
    }
}

extern "C" void kernel_launch(void* const* d_in, const int* in_sizes, int n_in,
                              void* d_out, int out_size, void* d_ws, size_t ws_size,
                              hipStream_t stream) {
    const float* pc  = (const float*)d_in[0];
    const float* ps  = (const float*)d_in[1];
    const float* ph  = (const float*)d_in[2];
    const float* sem = (const float*)d_in[3];
    const float* av  = (const float*)d_in[4];
    float* out = (float*)d_out;
    const int B = in_sizes[0] / (3 * KK);
    (void)d_ws; (void)ws_size; (void)n_in; (void)out_size;

    fused2_suppress_kernel<<<dim3(B), dim3(NTHREADS), 0, stream>>>(pc, ps, ph, sem, av, out);
}

// Round 11
// 69.103 us; speedup vs baseline: 1.6977x; 1.6977x over previous
//
#include <hip/hip_runtime.h>

#define KK 256
#define NCLS 18
#define MASK_BYTES_PER_BATCH (KK * KK)   // 65536

typedef unsigned long long ull;

// ---------------------------------------------------------------------------
// Phase 1 (r9-verified): per-pair AFFINE transition planes for both b_j values.
//   no event : a=1, β=0; A: a=tA0^tA1, β=tA0; B: M0/M1 value planes for b_j;
//   C: a(bj) = ~(c0^c1), β(bj) = c0,  cond = second_i < second_j.
// Word per (row i, lane): bit (4*p + q), pair q=j&3:
//   p0=A0 p1=A1 p2=B0 p3=B1 p4=isC p5=M0 p6=M1
// ---------------------------------------------------------------------------
__global__ __launch_bounds__(256)
void flags_kernel(const float* __restrict__ pc, const float* __restrict__ ps,
                  const float* __restrict__ ph, const float* __restrict__ sem,
                  const float* __restrict__ av,
                  unsigned char* __restrict__ ws_mask,
                  float* __restrict__ out)
{
#pragma clang fp contract(off)
    const int blk = blockIdx.x;
    const int b   = blk >> 4;
    const int g   = blk & 15;
    const int tid = threadIdx.x;

    __shared__ float sd0[KK], sd1[KK], sd2[KK], sd3[KK], sd4[KK], sd5[KK];
    __shared__ float sp[KK], sn[KK], sc0[KK], sc1[KK], sc2[KK];

    const float* pcb  = pc  + (size_t)b * 3 * KK;
    const float* psb  = ps  + (size_t)b * 3 * KK;
    const float* phb  = ph  + (size_t)b * 2 * KK;
    const float* semb = sem + (size_t)b * (2 + NCLS) * KK;
    const float* avb  = av  + (size_t)b * KK * 3;
    float* outb       = out + (size_t)b * KK * 28;

    {   // stage proposal `tid`'s derived data (identical float exprs to ref)
        const int k = tid;
        const float c0 = avb[k*3+0] + pcb[0*KK + k];
        const float c1 = avb[k*3+1] + pcb[1*KK + k];
        const float c2 = avb[k*3+2] + pcb[2*KK + k];
        const float s0 = psb[0*KK + k], s1 = psb[1*KK + k], s2 = psb[2*KK + k];
        const float h1 = phb[1*KK + k];
        const float v0 = s0 * h1, v1 = s1, v2 = s2 * h1;
        sd0[k] = (v0 + c0) - fabsf(s0);
        sd1[k] = (v0 + c0);
        sd2[k] = (v1 + c1) - fabsf(s1);
        sd3[k] = (v1 + c1);
        sd4[k] = (v2 + c2) - fabsf(s2);
        sd5[k] = (v2 + c2);
        sp[k]  = semb[0*KK + k];
        sn[k]  = semb[1*KK + k];
        sc0[k] = c0; sc1[k] = c1; sc2[k] = c2;
    }
    __syncthreads();

    // consecutive lanes = consecutive ROWS (j-reads broadcast, i-reads stride-1)
    const int rl = tid & 15;          // local row 0..15
    const int i  = g * 16 + rl;       // global row
    const int j0 = (tid >> 4) * 16;   // 16 j's per thread

    const float piv = sp[i], niv = sn[i];
    const float di0 = sd0[i], di1 = sd1[i], di2 = sd2[i];
    const float di3 = sd3[i], di4 = sd4[i], di5 = sd5[i];
    const float ci0 = sc0[i], ci1 = sc1[i], ci2 = sc2[i];

    unsigned W[4] = {0u, 0u, 0u, 0u};
#pragma unroll
    for (int t = 0; t < 16; ++t) {
        const int j = j0 + t;
        unsigned a0 = 1u, a1 = 1u, b0 = 0u, b1 = 0u, isC = 0u, mm0 = 0u, mm1 = 1u;
        if (j > i) {
            const float dx = ci0 - sc0[j];
            const float dy = ci1 - sc1[j];
            const float dz = ci2 - sc2[j];
            const float dist2 = dx*dx + dy*dy + dz*dz;
            if (dist2 < 9.0f) {
                const float e0 = sd0[j], e1 = sd1[j], e2 = sd2[j];
                const float e3 = sd3[j], e4 = sd4[j], e5 = sd5[j];
                const bool case0 = (e0 < di0) & (e1 > di1) & (e2 < di2)
                                 & (e3 > di3) & (e4 < di4) & (e5 > di5);
                const bool case1 = (e0 > di0) & (e1 < di1) & (e2 > di2)
                                 & (e3 < di3) & (e4 > di4) & (e5 < di5);
                if (case0) {
                    const unsigned tA0 = (piv < niv) ? 1u : 0u;
                    const unsigned tA1 = (niv < piv) ? 0u : 1u;
                    a0 = a1 = tA0 ^ tA1;
                    b0 = b1 = tA0;
                } else if (case1) {
                    const float pjv = sp[j], njv = sn[j];
                    mm0 = (pjv < njv) ? 1u : 0u;
                    mm1 = (njv < pjv) ? 0u : 1u;
                } else {
                    const bool ovx = ((e1 > di0) & (e1 < di1)) | ((di1 > e0) & (di1 < e1));
                    const bool ovy = ((e3 > di2) & (e3 < di3)) | ((di3 > e2) & (di3 < e3));
                    const bool ovz = ((e5 > di4) & (e5 < di5)) | ((di5 > e4) & (di5 < e5));
                    if (ovx & ovy & ovz) {
                        const float pjv = sp[j], njv = sn[j];
                        const unsigned c00 = (niv < njv) ? 1u : 0u;  // cond(0, bj=0)
                        const unsigned c10 = (piv < njv) ? 1u : 0u;  // cond(1, bj=0)
                        const unsigned c01 = (niv < pjv) ? 1u : 0u;  // cond(0, bj=1)
                        const unsigned c11 = (piv < pjv) ? 1u : 0u;  // cond(1, bj=1)
                        isC = 1u;
                        a0 = 1u ^ c00 ^ c10;  b0 = c00;
                        a1 = 1u ^ c01 ^ c11;  b1 = c01;
                    }
                }
            }
        }
        const unsigned s = a0 | (a1 << 4) | (b0 << 8) | (b1 << 12)
                         | (isC << 16) | (mm0 << 20) | (mm1 << 24);
        W[t >> 2] |= s << (t & 3);
    }

    uint4 w4;
    w4.x = W[0]; w4.y = W[1]; w4.z = W[2]; w4.w = W[3];
    *(uint4*)(ws_mask + (size_t)b * MASK_BYTES_PER_BATCH + i * KK + j0) = w4;

    // pass-through outputs for this block's k-slice [g*16, g*16+16)
    for (int s = tid; s < 16 * 28; s += 256) {
        const int kk = g * 16 + (s / 28);
        const int c  = s % 28;
        if (c == 8 || c == 9) continue;      // scores written by phase 2
        float val;
        if (c < 3)       val = (c == 0) ? sc0[kk] : ((c == 1) ? sc1[kk] : sc2[kk]);
        else if (c < 6)  val = psb[(c - 3) * KK + kk];
        else if (c < 8)  val = phb[(c - 6) * KK + kk];
        else             val = semb[(c - 8) * KK + kk];
        outb[(size_t)kk * 28 + c] = val;
    }
}

// ---------------------------------------------------------------------------
// Phase 2: one wave per batch. r7-verified front + tail, with DUAL-ENTRY
// commit (fixed0/fixed1 precomputed in parallel with ballots; row ends in a
// single select). Unconditional rows (r8/r10-verified), unroll-4 for ILP.
// ---------------------------------------------------------------------------
__global__ __launch_bounds__(64)
void suppress9_kernel(const float* __restrict__ sem,
                      const unsigned char* __restrict__ ws_mask,
                      float* __restrict__ out)
{
    const int b    = blockIdx.x;
    const int lane = threadIdx.x;

    __shared__ unsigned s_mask[KK * 64];   // 64 KB: linear copy of batch codes

    const float* semb = sem + (size_t)b * (2 + NCLS) * KK;
    float* outb       = out + (size_t)b * KK * 28;

    // stage codes: global -> LDS, 8 x 16B in flight per sweep group
    const uint4* gm = (const uint4*)(ws_mask + (size_t)b * MASK_BYTES_PER_BATCH);
    uint4* sm4 = (uint4*)s_mask;
    for (int so = 0; so < 64; so += 8) {
        uint4 v[8];
#pragma unroll
        for (int t = 0; t < 8; ++t) v[t] = gm[(so + t) * 64 + lane];
#pragma unroll
        for (int t = 0; t < 8; ++t) sm4[(so + t) * 64 + lane] = v[t];
    }

    float pj[4], nj[4];
#pragma unroll
    for (int q = 0; q < 4; ++q) {
        const int k = lane * 4 + q;
        pj[q] = semb[0*KK + k];
        nj[q] = semb[1*KK + k];
    }

    __syncthreads();   // staging complete

    unsigned bmask = 0;
    const ull belowR = __builtin_bitreverse64((1ull << lane) - 1ull);
    unsigned mcur = s_mask[lane];   // row 0

#pragma unroll 4
    for (int i = 0; i < KK - 1; ++i) {
        const unsigned mnext = s_mask[(i + 1) * 64 + lane];
        const unsigned m = mcur;
        const int slot = i & 3, owner = i >> 2;

        // b_start ballot: issued early, consumed late (off the VALU chain)
        const ull bsb = __ballot(((bmask >> slot) & 1u) != 0u);

        // plane extracts (state-independent; scheduler can hoist across rows)
        const unsigned A0n = m & 0xFu,         A1n = (m >> 4) & 0xFu;
        const unsigned B0n = (m >> 8) & 0xFu,  B1n = (m >> 12) & 0xFu;
        const unsigned isCn = (m >> 16) & 0xFu;
        const unsigned M0n = (m >> 20) & 0xFu, M1n = (m >> 24) & 0xFu;

        // plane selects by current b_j (bfi-shaped)
        const unsigned bm = bmask;
        const unsigned AV  = (A1n & bm) | (A0n & ~bm);
        const unsigned BV  = (B1n & bm) | (B0n & ~bm);
        const unsigned bmB = (M1n & bm) | (M0n & ~bm);
        const unsigned F0s = isCn & ~BV;
        const unsigned F1s = isCn & (AV ^ BV);

        // local affine exclusive prefix from entry 0 (r7-verified)
        const unsigned As = AV << 1;
        const unsigned Bs = BV << 1;
        const unsigned B2 = Bs ^ (As & (Bs << 1));
        const unsigned A2 = As & (As << 1);
        const unsigned av0 = B2 ^ (A2 & (B2 << 2));
        const unsigned y  = As | 1u;
        const unsigned z1 = y & ((y << 1) | 1u);
        const unsigned pa = z1 & ((z1 << 2) | 3u);
        const unsigned FS  = (AV & av0) ^ BV;   // bit3 = tl(0)
        const unsigned aTv = pa & AV;           // bit3 = lane-total a

        const ull b0m = __ballot((FS & 8u) != 0u);
        const ull b1m = __ballot(((FS ^ aTv) & 8u) != 0u);

        // dual-entry commit words: computed in parallel with ballots/tail
        const unsigned sv1 = av0 ^ pa;
        const unsigned flips0 = (F1s & av0) | (F0s & ~av0);
        const unsigned flips1 = (F1s & sv1) | (F0s & ~sv1);
        const unsigned nbm0 = bmB ^ flips0;
        const unsigned nbm1 = bmB ^ flips1;

        // segmented-scan tail (r7-verified)
        const ull nm  = b0m & ~b1m;
        const ull cm  = ~(b0m ^ b1m);
        const ull cmr = __builtin_bitreverse64(cm);
        const ull nmr = __builtin_bitreverse64(nm);
        const ull Wr  = __builtin_bitreverse64(b0m);
        const ull cbr = cmr & belowR;
        const ull lb  = cbr & (0ull - cbr);
        const unsigned vK = ((Wr & lb) != 0ull) ? 1u : 0u;
        const ull betw = belowR & (lb - 1ull);
        const unsigned par = (unsigned)__builtin_popcountll(nmr & betw) & 1u;
        const unsigned b_start = (unsigned)((bsb >> owner) & 1ull);
        const unsigned excl = ((cbr != 0ull) ? vK : b_start) ^ par;
        const ull lbA = cmr & (0ull - cmr);
        const unsigned vKA = ((Wr & lbA) != 0ull) ? 1u : 0u;
        const unsigned parA = (unsigned)__builtin_popcountll(nmr & (lbA - 1ull)) & 1u;
        const unsigned bfin = ((cmr != 0ull) ? vKA : b_start) ^ parA;

        // owner-fixed commit variants (bfin-dependent, parallel with excl path)
        const unsigned keep = ~(1u << slot);
        const unsigned ins  = bfin << slot;
        const unsigned fixed0 = (lane == owner) ? ((nbm0 & keep) | ins) : nbm0;
        const unsigned fixed1 = (lane == owner) ? ((nbm1 & keep) | ins) : nbm1;

        // single select ends the row
        bmask = excl ? fixed1 : fixed0;
        mcur = mnext;
    }

#pragma unroll
    for (int q = 0; q < 4; ++q) {
        const int k = lane * 4 + q;
        const unsigned bq = (bmask >> q) & 1u;
        outb[k*28 + 8] = bq ? nj[q] : pj[q];
        outb[k*28 + 9] = bq ? pj[q] : nj[q];
    }
}

// ---------------------------------------------------------------------------
// Fallback (round-1 verified kernel) in case ws_size is too small.
// ---------------------------------------------------------------------------
__device__ __forceinline__ unsigned compose2(unsigned a, unsigned b) {
    unsigned r0 = (b >> (a & 1u)) & 1u;
    unsigned r1 = (b >> ((a >> 1) & 1u)) & 1u;
    return r0 | (r1 << 1u);
}

__global__ __launch_bounds__(64)
void proposal_suppress_kernel(const float* __restrict__ pc, const float* __restrict__ ps,
                              const float* __restrict__ ph, const float* __restrict__ sem,
                              const float* __restrict__ av, float* __restrict__ out)
{
#pragma clang fp contract(off)
    const int b    = blockIdx.x;
    const int lane = threadIdx.x;

    __shared__ float s_p[KK], s_n[KK], s_d[KK][6], s_c[KK][3];

    const float* pcb  = pc  + (size_t)b * 3 * KK;
    const float* psb  = ps  + (size_t)b * 3 * KK;
    const float* phb  = ph  + (size_t)b * 2 * KK;
    const float* semb = sem + (size_t)b * (2 + NCLS) * KK;
    const float* avb  = av  + (size_t)b * KK * 3;
    float* outb       = out + (size_t)b * KK * 28;

    float pj[4], nj[4], dj[4][6], cj[4][3];
    unsigned Ljm = 0, Gjm = 0, bmask = 0;

#pragma unroll
    for (int q = 0; q < 4; ++q) {
        const int k = lane * 4 + q;
        const float c0 = avb[k*3+0] + pcb[0*KK + k];
        const float c1 = avb[k*3+1] + pcb[1*KK + k];
        const float c2 = avb[k*3+2] + pcb[2*KK + k];
        const float s0 = psb[0*KK + k], s1 = psb[1*KK + k], s2 = psb[2*KK + k];
        const float h0 = phb[0*KK + k], h1 = phb[1*KK + k];
        const float v0 = s0 * h1, v1 = s1, v2 = s2 * h1;
        float d[6];
        d[0] = (v0 + c0) - fabsf(s0); d[1] = (v0 + c0);
        d[2] = (v1 + c1) - fabsf(s1); d[3] = (v1 + c1);
        d[4] = (v2 + c2) - fabsf(s2); d[5] = (v2 + c2);
        const float p = semb[0*KK + k];
        const float n = semb[1*KK + k];
        cj[q][0] = c0; cj[q][1] = c1; cj[q][2] = c2;
#pragma unroll
        for (int m = 0; m < 6; ++m) dj[q][m] = d[m];
        pj[q] = p; nj[q] = n;
        if (p < n) Ljm |= 1u << q;
        if (n < p) Gjm |= 1u << q;
        s_p[k] = p; s_n[k] = n;
#pragma unroll
        for (int m = 0; m < 6; ++m) s_d[k][m] = d[m];
        s_c[k][0] = c0; s_c[k][1] = c1; s_c[k][2] = c2;
        outb[k*28 + 0] = c0; outb[k*28 + 1] = c1; outb[k*28 + 2] = c2;
        outb[k*28 + 3] = s0; outb[k*28 + 4] = s1; outb[k*28 + 5] = s2;
        outb[k*28 + 6] = h0; outb[k*28 + 7] = h1;
#pragma unroll
        for (int cc = 0; cc < NCLS; ++cc)
            outb[k*28 + 10 + cc] = semb[(2 + cc)*KK + k];
    }
    __syncthreads();

    const unsigned ID = 2u;
    for (int i = 0; i < KK - 1; ++i) {
        const float piv = s_p[i], niv = s_n[i];
        const float di0 = s_d[i][0], di1 = s_d[i][1], di2 = s_d[i][2];
        const float di3 = s_d[i][3], di4 = s_d[i][4], di5 = s_d[i][5];
        const float ci0 = s_c[i][0], ci1 = s_c[i][1], ci2 = s_c[i][2];
        const unsigned tA = (piv < niv ? 1u : 0u) | ((niv < piv ? 0u : 1u) << 1);
        const int owner = i >> 2, slot = i & 3;

        unsigned tq[4];
        unsigned Cq = 0, cc0m = 0, cc1m = 0;
        unsigned tl = ID;
#pragma unroll
        for (int q = 0; q < 4; ++q) {
            const int j = lane * 4 + q;
            unsigned t = ID;
            if (j > i) {
                const float dx = ci0 - cj[q][0];
                const float dy = ci1 - cj[q][1];
                const float dz = ci2 - cj[q][2];
                const float dist2 = dx*dx + dy*dy + dz*dz;
                if (dist2 < 9.0f) {
                    const bool case0 = (dj[q][0] < di0) & (dj[q][1] > di1)
                                     & (dj[q][2] < di2) & (dj[q][3] > di3)
                                     & (dj[q][4] < di4) & (dj[q][5] > di5);
                    const bool case1 = (dj[q][0] > di0) & (dj[q][1] < di1)
                                     & (dj[q][2] > di2) & (dj[q][3] < di3)
                                     & (dj[q][4] > di4) & (dj[q][5] < di5);
                    if (case0) {
                        t = tA;
                    } else if (case1) {
                        const unsigned bj = (bmask >> q) & 1u;
                        const unsigned nb = bj ? (((Gjm >> q) & 1u) ? 0u : 1u)
                                               : (((Ljm >> q) & 1u) ? 1u : 0u);
                        bmask = (bmask & ~(1u << q)) | (nb << q);
                    } else {
                        const bool ovx = ((dj[q][1] > di0) & (dj[q][1] < di1))
                                       | ((di1 > dj[q][0]) & (di1 < dj[q][1]));
                        const bool ovy = ((dj[q][3] > di2) & (dj[q][3] < di3))
                                       | ((di3 > dj[q][2]) & (di3 < dj[q][3]));
                        const bool ovz = ((dj[q][5] > di4) & (dj[q][5] < di5))
                                       | ((di5 > dj[q][4]) & (di5 < dj[q][5]));
                        if (ovx & ovy & ovz) {
                            const unsigned bj = (bmask >> q) & 1u;
                            const float sj = bj ? pj[q] : nj[q];
                            const unsigned c0b = (niv < sj) ? 1u : 0u;
                            const unsigned c1b = (piv < sj) ? 1u : 0u;
                            t = c0b | ((c1b ^ 1u) << 1u);
                            Cq |= 1u << q; cc0m |= c0b << q; cc1m |= c1b << q;
                        }
                    }
                }
            }
            tq[q] = t;
            tl = compose2(tl, t);
        }

        const ull any = __ballot((tl != ID) || (Cq != 0));
        if (any == 0ull) continue;

        const unsigned b_start = (((unsigned)__shfl((int)bmask, owner, 64)) >> slot) & 1u;

        unsigned incl = tl;
#pragma unroll
        for (int off = 1; off < 64; off <<= 1) {
            const unsigned other = (unsigned)__shfl_up((int)incl, (unsigned)off, 64);
            if (lane >= off) incl = compose2(other, incl);
        }
        const unsigned total = (unsigned)__shfl((int)incl, 63, 64);
        const unsigned upv   = (unsigned)__shfl_up((int)incl, 1u, 64);
        const unsigned excl  = (lane == 0) ? ID : upv;

        unsigned cur = (excl >> b_start) & 1u;
#pragma unroll
        for (int q = 0; q < 4; ++q) {
            if ((Cq >> q) & 1u) {
                const unsigned cond = cur ? ((cc1m >> q) & 1u) : ((cc0m >> q) & 1u);
                if (!cond) bmask ^= (1u << q);
            }
            cur = (tq[q] >> cur) & 1u;
        }
        if (lane == owner) {
            const unsigned nbi = (total >> b_start) & 1u;
            bmask = (bmask & ~(1u << slot)) | (nbi << slot);
        }
    }

#pragma unroll
    for (int q = 0; q < 4; ++q) {
        const int k = lane * 4 + q;
        const unsigned bq = (bmask >> q) & 1u;
        outb[k*28 + 8] = bq ? nj[q] : pj[q];
        outb[k*28 + 9] = bq ? pj[q] : nj[q];
    }
}

extern "C" void kernel_launch(void* const* d_in, const int* in_sizes, int n_in,
                              void* d_out, int out_size, void* d_ws, size_t ws_size,
                              hipStream_t stream) {
    const float* pc  = (const float*)d_in[0];
    const float* ps  = (const float*)d_in[1];
    const float* ph  = (const float*)d_in[2];
    const float* sem = (const float*)d_in[3];
    const float* av  = (const float*)d_in[4];
    float* out = (float*)d_out;
    const int B = in_sizes[0] / (3 * KK);

    const size_t need = (size_t)B * MASK_BYTES_PER_BATCH;
    if (ws_size >= need) {
        unsigned char* wm = (unsigned char*)d_ws;
        flags_kernel<<<dim3(B * 16), dim3(256), 0, stream>>>(pc, ps, ph, sem, av, wm, out);
        suppress9_kernel<<<dim3(B), dim3(64), 0, stream>>>(sem, wm, out);
    } else {
        proposal_suppress_kernel<<<dim3(B), dim3(64), 0, stream>>>(pc, ps, ph, sem, av, out);
    }
}

// Round 12
// 46.440 us; speedup vs baseline: 2.5263x; 1.4880x over previous
//
#include <hip/hip_runtime.h>

#define KK 256
#define NCLS 18
#define MASK_BYTES_PER_BATCH (KK * KK)   // 65536

typedef unsigned long long ull;

// ---------------------------------------------------------------------------
// Phase 1 (r7-verified): per-pair AFFINE transition planes for both b_j values.
//   no event : a=1, β=0; A: a=tA0^tA1, β=tA0; B: M0/M1 value planes for b_j;
//   C: a(bj) = ~(c0^c1), β(bj) = c0,  cond = second_i < second_j.
// Word per (row i, lane): bit (4*p + q), pair q=j&3:
//   p0=A0 p1=A1 p2=B0 p3=B1 p4=isC p5=M0 p6=M1
// ws_sum[i]: bit0 = row has any event, bit1 = row has A or C event.
// ---------------------------------------------------------------------------
__global__ __launch_bounds__(256)
void flags_kernel(const float* __restrict__ pc, const float* __restrict__ ps,
                  const float* __restrict__ ph, const float* __restrict__ sem,
                  const float* __restrict__ av,
                  unsigned char* __restrict__ ws_mask,
                  unsigned char* __restrict__ ws_sum,
                  float* __restrict__ out)
{
#pragma clang fp contract(off)
    const int blk = blockIdx.x;
    const int b   = blk >> 4;
    const int g   = blk & 15;
    const int tid = threadIdx.x;

    // SoA LDS: stride-1 -> conflict-free for both i- and j-access patterns
    __shared__ float sd0[KK], sd1[KK], sd2[KK], sd3[KK], sd4[KK], sd5[KK];
    __shared__ float sp[KK], sn[KK], sc0[KK], sc1[KK], sc2[KK];
    __shared__ unsigned rowsum[16];

    const float* pcb  = pc  + (size_t)b * 3 * KK;
    const float* psb  = ps  + (size_t)b * 3 * KK;
    const float* phb  = ph  + (size_t)b * 2 * KK;
    const float* semb = sem + (size_t)b * (2 + NCLS) * KK;
    const float* avb  = av  + (size_t)b * KK * 3;
    float* outb       = out + (size_t)b * KK * 28;

    {   // stage proposal `tid`'s derived data (identical float exprs to ref)
        const int k = tid;
        const float c0 = avb[k*3+0] + pcb[0*KK + k];
        const float c1 = avb[k*3+1] + pcb[1*KK + k];
        const float c2 = avb[k*3+2] + pcb[2*KK + k];
        const float s0 = psb[0*KK + k], s1 = psb[1*KK + k], s2 = psb[2*KK + k];
        const float h1 = phb[1*KK + k];
        const float v0 = s0 * h1, v1 = s1, v2 = s2 * h1;
        sd0[k] = (v0 + c0) - fabsf(s0);
        sd1[k] = (v0 + c0);
        sd2[k] = (v1 + c1) - fabsf(s1);
        sd3[k] = (v1 + c1);
        sd4[k] = (v2 + c2) - fabsf(s2);
        sd5[k] = (v2 + c2);
        sp[k]  = semb[0*KK + k];
        sn[k]  = semb[1*KK + k];
        sc0[k] = c0; sc1[k] = c1; sc2[k] = c2;
    }
    if (tid < 16) rowsum[tid] = 0;
    __syncthreads();

    // consecutive lanes = consecutive ROWS (j-reads broadcast, i-reads stride-1)
    const int rl = tid & 15;          // local row 0..15
    const int i  = g * 16 + rl;       // global row
    const int j0 = (tid >> 4) * 16;   // 16 j's per thread

    const float piv = sp[i], niv = sn[i];
    const float di0 = sd0[i], di1 = sd1[i], di2 = sd2[i];
    const float di3 = sd3[i], di4 = sd4[i], di5 = sd5[i];
    const float ci0 = sc0[i], ci1 = sc1[i], ci2 = sc2[i];

    unsigned W[4] = {0u, 0u, 0u, 0u};
    bool evt = false, evtAC = false;
#pragma unroll
    for (int t = 0; t < 16; ++t) {
        const int j = j0 + t;
        unsigned a0 = 1u, a1 = 1u, b0 = 0u, b1 = 0u, isC = 0u, mm0 = 0u, mm1 = 1u;
        if (j > i) {
            const float dx = ci0 - sc0[j];
            const float dy = ci1 - sc1[j];
            const float dz = ci2 - sc2[j];
            const float dist2 = dx*dx + dy*dy + dz*dz;
            if (dist2 < 9.0f) {
                const float e0 = sd0[j], e1 = sd1[j], e2 = sd2[j];
                const float e3 = sd3[j], e4 = sd4[j], e5 = sd5[j];
                const bool case0 = (e0 < di0) & (e1 > di1) & (e2 < di2)
                                 & (e3 > di3) & (e4 < di4) & (e5 > di5);
                const bool case1 = (e0 > di0) & (e1 < di1) & (e2 > di2)
                                 & (e3 < di3) & (e4 > di4) & (e5 < di5);
                if (case0) {
                    const unsigned tA0 = (piv < niv) ? 1u : 0u;
                    const unsigned tA1 = (niv < piv) ? 0u : 1u;
                    a0 = a1 = tA0 ^ tA1;
                    b0 = b1 = tA0;
                    evt = true; evtAC = true;
                } else if (case1) {
                    const float pjv = sp[j], njv = sn[j];
                    mm0 = (pjv < njv) ? 1u : 0u;
                    mm1 = (njv < pjv) ? 0u : 1u;
                    evt = true;
                } else {
                    const bool ovx = ((e1 > di0) & (e1 < di1)) | ((di1 > e0) & (di1 < e1));
                    const bool ovy = ((e3 > di2) & (e3 < di3)) | ((di3 > e2) & (di3 < e3));
                    const bool ovz = ((e5 > di4) & (e5 < di5)) | ((di5 > e4) & (di5 < e5));
                    if (ovx & ovy & ovz) {
                        const float pjv = sp[j], njv = sn[j];
                        const unsigned c00 = (niv < njv) ? 1u : 0u;  // cond(0, bj=0)
                        const unsigned c10 = (piv < njv) ? 1u : 0u;  // cond(1, bj=0)
                        const unsigned c01 = (niv < pjv) ? 1u : 0u;  // cond(0, bj=1)
                        const unsigned c11 = (piv < pjv) ? 1u : 0u;  // cond(1, bj=1)
                        isC = 1u;
                        a0 = 1u ^ c00 ^ c10;  b0 = c00;
                        a1 = 1u ^ c01 ^ c11;  b1 = c01;
                        evt = true; evtAC = true;
                    }
                }
            }
        }
        const unsigned s = a0 | (a1 << 4) | (b0 << 8) | (b1 << 12)
                         | (isC << 16) | (mm0 << 20) | (mm1 << 24);
        W[t >> 2] |= s << (t & 3);
    }

    uint4 w4;
    w4.x = W[0]; w4.y = W[1]; w4.z = W[2]; w4.w = W[3];
    *(uint4*)(ws_mask + (size_t)b * MASK_BYTES_PER_BATCH + i * KK + j0) = w4;

    const unsigned f = (evt ? 1u : 0u) | (evtAC ? 2u : 0u);
    if (f) atomicOr(&rowsum[rl], f);

    // pass-through outputs for this block's k-slice [g*16, g*16+16)
    for (int s = tid; s < 16 * 28; s += 256) {
        const int kk = g * 16 + (s / 28);
        const int c  = s % 28;
        if (c == 8 || c == 9) continue;      // scores written by phase 2
        float val;
        if (c < 3)       val = (c == 0) ? sc0[kk] : ((c == 1) ? sc1[kk] : sc2[kk]);
        else if (c < 6)  val = psb[(c - 3) * KK + kk];
        else if (c < 8)  val = phb[(c - 6) * KK + kk];
        else             val = semb[(c - 8) * KK + kk];
        outb[(size_t)kk * 28 + c] = val;
    }

    __syncthreads();
    if (tid < 16) {
        ws_sum[b * KK + g * 16 + tid] = (unsigned char)rowsum[tid];
    }
}

// ---------------------------------------------------------------------------
// Phase 2 (r7 suppress7 verbatim + B-only fast path): one wave per batch.
// Bulk LDS staging + distance-1 prefetch rotation; affine row body; rows with
// no A/C events collapse to bmask = (M1&bm)|(M0&~bm) (provably equivalent).
// ---------------------------------------------------------------------------
__global__ __launch_bounds__(64)
void suppress10_kernel(const float* __restrict__ sem,
                       const unsigned char* __restrict__ ws_mask,
                       const unsigned char* __restrict__ ws_sum,
                       float* __restrict__ out)
{
    const int b    = blockIdx.x;
    const int lane = threadIdx.x;

    __shared__ unsigned s_mask[KK * 64];   // 64 KB: linear copy of batch codes

    const float* semb = sem + (size_t)b * (2 + NCLS) * KK;
    float* outb       = out + (size_t)b * KK * 28;

    // stage codes: global -> LDS, 8 x 16B in flight per sweep group
    const uint4* gm = (const uint4*)(ws_mask + (size_t)b * MASK_BYTES_PER_BATCH);
    uint4* sm4 = (uint4*)s_mask;
    for (int so = 0; so < 64; so += 8) {
        uint4 v[8];
#pragma unroll
        for (int t = 0; t < 8; ++t) v[t] = gm[(so + t) * 64 + lane];
#pragma unroll
        for (int t = 0; t < 8; ++t) sm4[(so + t) * 64 + lane] = v[t];
    }

    float pj[4], nj[4];
#pragma unroll
    for (int q = 0; q < 4; ++q) {
        const int k = lane * 4 + q;
        pj[q] = semb[0*KK + k];
        nj[q] = semb[1*KK + k];
    }

    // row-activity bitmaps via ballots
    const unsigned char* sbp = ws_sum + b * KK;
    const unsigned sb0 = sbp[lane], sb1 = sbp[64 + lane],
                   sb2 = sbp[128 + lane], sb3 = sbp[192 + lane];
    const ull any0 = __ballot(sb0 & 1u), ac0 = __ballot(sb0 & 2u);
    const ull any1 = __ballot(sb1 & 1u), ac1 = __ballot(sb1 & 2u);
    const ull any2 = __ballot(sb2 & 1u), ac2 = __ballot(sb2 & 2u);
    const ull any3 = __ballot(sb3 & 1u), ac3 = __ballot(sb3 & 2u);

    __syncthreads();   // staging complete

    unsigned bmask = 0;
    const ull belowR = __builtin_bitreverse64((1ull << lane) - 1ull);

#define ROWBODY(i_) { \
        const unsigned m = mcur; \
        const int slot = (i_) & 3, owner = (i_) >> 2; \
        const ull bsb = __ballot(((bmask >> slot) & 1u) != 0u); \
        const unsigned b_start = (unsigned)((bsb >> owner) & 1ull); \
        const unsigned A0n = m & 0xFu,         A1n = (m >> 4) & 0xFu; \
        const unsigned B0n = (m >> 8) & 0xFu,  B1n = (m >> 12) & 0xFu; \
        const unsigned isCn = (m >> 16) & 0xFu; \
        const unsigned M0n = (m >> 20) & 0xFu, M1n = (m >> 24) & 0xFu; \
        const unsigned bm = bmask; \
        const unsigned AV  = (A1n & bm) | (A0n & ~bm); \
        const unsigned BV  = (B1n & bm) | (B0n & ~bm); \
        const unsigned bmB = (M1n & bm) | (M0n & ~bm); \
        const unsigned F0s = isCn & ~BV; \
        const unsigned F1s = isCn & (AV ^ BV); \
        /* local affine exclusive prefix from entry 0 */ \
        const unsigned As = AV << 1; \
        const unsigned Bs = BV << 1; \
        const unsigned B2 = Bs ^ (As & (Bs << 1)); \
        const unsigned A2 = As & (As << 1); \
        const unsigned av0 = B2 ^ (A2 & (B2 << 2)); \
        const unsigned y  = As | 1u; \
        const unsigned z1 = y & ((y << 1) | 1u); \
        const unsigned pa = z1 & ((z1 << 2) | 3u); \
        const unsigned FS  = (AV & av0) ^ BV;   /* bit3 = tl(0) */ \
        const unsigned aTv = pa & AV;           /* bit3 = lane-total a */ \
        const ull b0m = __ballot((FS & 8u) != 0u); \
        const ull b1m = __ballot(((FS ^ aTv) & 8u) != 0u); \
        /* segmented-scan tail */ \
        const ull nm  = b0m & ~b1m; \
        const ull cm  = ~(b0m ^ b1m); \
        const ull cmr = __builtin_bitreverse64(cm); \
        const ull nmr = __builtin_bitreverse64(nm); \
        const ull Wr  = __builtin_bitreverse64(b0m); \
        const ull cbr = cmr & belowR; \
        const ull lb  = cbr & (0ull - cbr); \
        const unsigned vK = ((Wr & lb) != 0ull) ? 1u : 0u; \
        const ull betw = belowR & (lb - 1ull); \
        const unsigned par = (unsigned)__builtin_popcountll(nmr & betw) & 1u; \
        const unsigned excl = ((cbr != 0ull) ? vK : b_start) ^ par; \
        const ull lbA = cmr & (0ull - cmr); \
        const unsigned vKA = ((Wr & lbA) != 0ull) ? 1u : 0u; \
        const unsigned parA = (unsigned)__builtin_popcountll(nmr & (lbA - 1ull)) & 1u; \
        const unsigned bfin = ((cmr != 0ull) ? vKA : b_start) ^ parA; \
        /* C flips from per-step entry states; B effects via M planes */ \
        const unsigned Emask = (0u - excl) & 0xFu; \
        const unsigned sv = av0 ^ (pa & Emask); \
        const unsigned flips = (F1s & sv) | (F0s & ~sv); \
        unsigned nbm = bmB ^ flips; \
        const unsigned fixed = (nbm & ~(1u << slot)) | (bfin << slot); \
        bmask = (lane == owner) ? fixed : nbm; }

#define RUNCHUNK(W_, ANY, AC, NROWS) \
    for (int bb = 0; bb < (NROWS); ++bb) { \
        const int i_ = ((W_) << 6) + bb; \
        const unsigned mnext = s_mask[(i_ + 1) * 64 + lane]; \
        if (((ANY) >> bb) & 1ull) { \
            if (!(((AC) >> bb) & 1ull)) { \
                /* B-only row: full body provably reduces to the M-select */ \
                const unsigned m = mcur; \
                const unsigned M0n = (m >> 20) & 0xFu, M1n = (m >> 24) & 0xFu; \
                bmask = (M1n & bmask) | (M0n & ~bmask); \
            } else ROWBODY(i_) \
        } \
        mcur = mnext; \
    }

    unsigned mcur = s_mask[lane];   // row 0
    RUNCHUNK(0, any0, ac0, 64)
    RUNCHUNK(1, any1, ac1, 64)
    RUNCHUNK(2, any2, ac2, 64)
    RUNCHUNK(3, any3, ac3, 63)

#undef RUNCHUNK
#undef ROWBODY

#pragma unroll
    for (int q = 0; q < 4; ++q) {
        const int k = lane * 4 + q;
        const unsigned bq = (bmask >> q) & 1u;
        outb[k*28 + 8] = bq ? nj[q] : pj[q];
        outb[k*28 + 9] = bq ? pj[q] : nj[q];
    }
}

// ---------------------------------------------------------------------------
// Fallback (round-1 verified kernel) in case ws_size is too small.
// ---------------------------------------------------------------------------
__device__ __forceinline__ unsigned compose2(unsigned a, unsigned b) {
    unsigned r0 = (b >> (a & 1u)) & 1u;
    unsigned r1 = (b >> ((a >> 1) & 1u)) & 1u;
    return r0 | (r1 << 1u);
}

__global__ __launch_bounds__(64)
void proposal_suppress_kernel(const float* __restrict__ pc, const float* __restrict__ ps,
                              const float* __restrict__ ph, const float* __restrict__ sem,
                              const float* __restrict__ av, float* __restrict__ out)
{
#pragma clang fp contract(off)
    const int b    = blockIdx.x;
    const int lane = threadIdx.x;

    __shared__ float s_p[KK], s_n[KK], s_d[KK][6], s_c[KK][3];

    const float* pcb  = pc  + (size_t)b * 3 * KK;
    const float* psb  = ps  + (size_t)b * 3 * KK;
    const float* phb  = ph  + (size_t)b * 2 * KK;
    const float* semb = sem + (size_t)b * (2 + NCLS) * KK;
    const float* avb  = av  + (size_t)b * KK * 3;
    float* outb       = out + (size_t)b * KK * 28;

    float pj[4], nj[4], dj[4][6], cj[4][3];
    unsigned Ljm = 0, Gjm = 0, bmask = 0;

#pragma unroll
    for (int q = 0; q < 4; ++q) {
        const int k = lane * 4 + q;
        const float c0 = avb[k*3+0] + pcb[0*KK + k];
        const float c1 = avb[k*3+1] + pcb[1*KK + k];
        const float c2 = avb[k*3+2] + pcb[2*KK + k];
        const float s0 = psb[0*KK + k], s1 = psb[1*KK + k], s2 = psb[2*KK + k];
        const float h0 = phb[0*KK + k], h1 = phb[1*KK + k];
        const float v0 = s0 * h1, v1 = s1, v2 = s2 * h1;
        float d[6];
        d[0] = (v0 + c0) - fabsf(s0); d[1] = (v0 + c0);
        d[2] = (v1 + c1) - fabsf(s1); d[3] = (v1 + c1);
        d[4] = (v2 + c2) - fabsf(s2); d[5] = (v2 + c2);
        const float p = semb[0*KK + k];
        const float n = semb[1*KK + k];
        cj[q][0] = c0; cj[q][1] = c1; cj[q][2] = c2;
#pragma unroll
        for (int m = 0; m < 6; ++m) dj[q][m] = d[m];
        pj[q] = p; nj[q] = n;
        if (p < n) Ljm |= 1u << q;
        if (n < p) Gjm |= 1u << q;
        s_p[k] = p; s_n[k] = n;
#pragma unroll
        for (int m = 0; m < 6; ++m) s_d[k][m] = d[m];
        s_c[k][0] = c0; s_c[k][1] = c1; s_c[k][2] = c2;
        outb[k*28 + 0] = c0; outb[k*28 + 1] = c1; outb[k*28 + 2] = c2;
        outb[k*28 + 3] = s0; outb[k*28 + 4] = s1; outb[k*28 + 5] = s2;
        outb[k*28 + 6] = h0; outb[k*28 + 7] = h1;
#pragma unroll
        for (int cc = 0; cc < NCLS; ++cc)
            outb[k*28 + 10 + cc] = semb[(2 + cc)*KK + k];
    }
    __syncthreads();

    const unsigned ID = 2u;
    for (int i = 0; i < KK - 1; ++i) {
        const float piv = s_p[i], niv = s_n[i];
        const float di0 = s_d[i][0], di1 = s_d[i][1], di2 = s_d[i][2];
        const float di3 = s_d[i][3], di4 = s_d[i][4], di5 = s_d[i][5];
        const float ci0 = s_c[i][0], ci1 = s_c[i][1], ci2 = s_c[i][2];
        const unsigned tA = (piv < niv ? 1u : 0u) | ((niv < piv ? 0u : 1u) << 1);
        const int owner = i >> 2, slot = i & 3;

        unsigned tq[4];
        unsigned Cq = 0, cc0m = 0, cc1m = 0;
        unsigned tl = ID;
#pragma unroll
        for (int q = 0; q < 4; ++q) {
            const int j = lane * 4 + q;
            unsigned t = ID;
            if (j > i) {
                const float dx = ci0 - cj[q][0];
                const float dy = ci1 - cj[q][1];
                const float dz = ci2 - cj[q][2];
                const float dist2 = dx*dx + dy*dy + dz*dz;
                if (dist2 < 9.0f) {
                    const bool case0 = (dj[q][0] < di0) & (dj[q][1] > di1)
                                     & (dj[q][2] < di2) & (dj[q][3] > di3)
                                     & (dj[q][4] < di4) & (dj[q][5] > di5);
                    const bool case1 = (dj[q][0] > di0) & (dj[q][1] < di1)
                                     & (dj[q][2] > di2) & (dj[q][3] < di3)
                                     & (dj[q][4] > di4) & (dj[q][5] < di5);
                    if (case0) {
                        t = tA;
                    } else if (case1) {
                        const unsigned bj = (bmask >> q) & 1u;
                        const unsigned nb = bj ? (((Gjm >> q) & 1u) ? 0u : 1u)
                                               : (((Ljm >> q) & 1u) ? 1u : 0u);
                        bmask = (bmask & ~(1u << q)) | (nb << q);
                    } else {
                        const bool ovx = ((dj[q][1] > di0) & (dj[q][1] < di1))
                                       | ((di1 > dj[q][0]) & (di1 < dj[q][1]));
                        const bool ovy = ((dj[q][3] > di2) & (dj[q][3] < di3))
                                       | ((di3 > dj[q][2]) & (di3 < dj[q][3]));
                        const bool ovz = ((dj[q][5] > di4) & (dj[q][5] < di5))
                                       | ((di5 > dj[q][4]) & (di5 < dj[q][5]));
                        if (ovx & ovy & ovz) {
                            const unsigned bj = (bmask >> q) & 1u;
                            const float sj = bj ? pj[q] : nj[q];
                            const unsigned c0b = (niv < sj) ? 1u : 0u;
                            const unsigned c1b = (piv < sj) ? 1u : 0u;
                            t = c0b | ((c1b ^ 1u) << 1u);
                            Cq |= 1u << q; cc0m |= c0b << q; cc1m |= c1b << q;
                        }
                    }
                }
            }
            tq[q] = t;
            tl = compose2(tl, t);
        }

        const ull any = __ballot((tl != ID) || (Cq != 0));
        if (any == 0ull) continue;

        const unsigned b_start = (((unsigned)__shfl((int)bmask, owner, 64)) >> slot) & 1u;

        unsigned incl = tl;
#pragma unroll
        for (int off = 1; off < 64; off <<= 1) {
            const unsigned other = (unsigned)__shfl_up((int)incl, (unsigned)off, 64);
            if (lane >= off) incl = compose2(other, incl);
        }
        const unsigned total = (unsigned)__shfl((int)incl, 63, 64);
        const unsigned upv   = (unsigned)__shfl_up((int)incl, 1u, 64);
        const unsigned excl  = (lane == 0) ? ID : upv;

        unsigned cur = (excl >> b_start) & 1u;
#pragma unroll
        for (int q = 0; q < 4; ++q) {
            if ((Cq >> q) & 1u) {
                const unsigned cond = cur ? ((cc1m >> q) & 1u) : ((cc0m >> q) & 1u);
                if (!cond) bmask ^= (1u << q);
            }
            cur = (tq[q] >> cur) & 1u;
        }
        if (lane == owner) {
            const unsigned nbi = (total >> b_start) & 1u;
            bmask = (bmask & ~(1u << slot)) | (nbi << slot);
        }
    }

#pragma unroll
    for (int q = 0; q < 4; ++q) {
        const int k = lane * 4 + q;
        const unsigned bq = (bmask >> q) & 1u;
        outb[k*28 + 8] = bq ? nj[q] : pj[q];
        outb[k*28 + 9] = bq ? pj[q] : nj[q];
    }
}

extern "C" void kernel_launch(void* const* d_in, const int* in_sizes, int n_in,
                              void* d_out, int out_size, void* d_ws, size_t ws_size,
                              hipStream_t stream) {
    const float* pc  = (const float*)d_in[0];
    const float* ps  = (const float*)d_in[1];
    const float* ph  = (const float*)d_in[2];
    const float* sem = (const float*)d_in[3];
    const float* av  = (const float*)d_in[4];
    float* out = (float*)d_out;
    const int B = in_sizes[0] / (3 * KK);

    const size_t need = (size_t)B * MASK_BYTES_PER_BATCH + (size_t)B * KK;
    if (ws_size >= need) {
        unsigned char* wm   = (unsigned char*)d_ws;
        unsigned char* wsum = wm + (size_t)B * MASK_BYTES_PER_BATCH;
        flags_kernel<<<dim3(B * 16), dim3(256), 0, stream>>>(pc, ps, ph, sem, av, wm, wsum, out);
        suppress10_kernel<<<dim3(B), dim3(64), 0, stream>>>(sem, wm, wsum, out);
    } else {
        proposal_suppress_kernel<<<dim3(B), dim3(64), 0, stream>>>(pc, ps, ph, sem, av, out);
    }
}